// Round 9
// baseline (539.418 us; speedup 1.0000x reference)
//
#include <hip/hip_runtime.h>
#include <hip/hip_bf16.h>

// GAT: N=4096 nodes, IN_F=256, H=4 heads, D=64.
// K1 gat_prep : fused. blocks [0,256): h = x@W (fp32, 64x64 tile, 4x4 micro-tile,
//               fully-unrolled straight-line k-loop -> scheduler pipelines loads),
//               siT = <h,a1>*log2e, vv2T = {exp2(sj), exp2(0.2*sj)},
//               hTf bf16 fragment-major [h][j-chunk][nt][lane], sj-max partials.
//               blocks [256,2304): adj (64 MB int) -> adjb bitmask (2 MB),
//               8 int4 in flight/thread; streams concurrently with the GEMM.
// K2 gat_attn : masked softmax + PV via mfma_16x16x32_bf16.
//               m_i = leaky(si + max_j sj) upper bound -> pure-sum softmax.
//               64-row tiles x 4 heads x 2 j-splits; 256-j LDS windows double-
//               buffered (32KBx2), staged with contiguous-1KB global_load_lds;
//               masks+vv2 register-prefetched (drained free by window barrier).
// K3 gat_reduce: out = (p0+p1)/(l0+l1).

typedef __bf16 bf16x8 __attribute__((ext_vector_type(8)));
typedef float floatx4 __attribute__((ext_vector_type(4)));

#define LOG2E 1.4426950408889634f
#define NN 4096

__device__ __forceinline__ void gl16(const void* g, void* l) {
  __builtin_amdgcn_global_load_lds(
      (const __attribute__((address_space(1))) unsigned int*)g,
      (__attribute__((address_space(3))) unsigned int*)l, 16, 0, 0);
}

// ---------------- Kernel 1: fused prep + pack ----------------
// blocks [0,256): prep (it = b&63 -> 64-row tile, hh = b>>6)
// blocks [256,2304): pack (thread -> 4 mask bytes, 8 int4 in flight)
__global__ __launch_bounds__(256, 2) void gat_prep(
    const float* __restrict__ x, const float* __restrict__ W,
    const float* __restrict__ a1, const float* __restrict__ a2,
    const int* __restrict__ adj, __bf16* __restrict__ hTf,
    float* __restrict__ siT, float2* __restrict__ vv2T, float* __restrict__ sjm,
    unsigned char* __restrict__ adjb) {
  const int b = blockIdx.x;
  const int t = threadIdx.x;

  if (b >= 256) {  // ---- pack: adj -> bitmask, dword per thread ----
    const int T = (b - 256) * 256 + t;      // dword index, [0, 512K)
    const int* p = adj + (size_t)T * 32;    // 32 ints = 128 B contiguous
    int4 v[8];
#pragma unroll
    for (int j = 0; j < 8; ++j) v[j] = *(const int4*)(p + j * 4);
    unsigned int m = 0;
#pragma unroll
    for (int c = 0; c < 4; ++c) {
      int4 a = v[2 * c], bb = v[2 * c + 1];
      unsigned int mm = 0;
      mm |= (a.x != 0) ? 1u : 0u;
      mm |= (a.y != 0) ? 2u : 0u;
      mm |= (a.z != 0) ? 4u : 0u;
      mm |= (a.w != 0) ? 8u : 0u;
      mm |= (bb.x != 0) ? 16u : 0u;
      mm |= (bb.y != 0) ? 32u : 0u;
      mm |= (bb.z != 0) ? 64u : 0u;
      mm |= (bb.w != 0) ? 128u : 0u;
      m |= mm << (c * 8);
    }
    ((unsigned int*)adjb)[T] = m;
    return;
  }

  // ---- prep: 64 rows x 64 cols per block, 4x4 micro-tile per thread ----
  __shared__ float hl[64 * 68];
  __shared__ float sjb[64];
  const int it = b & 63, hh = b >> 6;
  const int i0 = it * 64, c0 = hh * 64;
  const int tr = t >> 4, tc = t & 15;   // 16 row-groups x 16 col-groups

  float acc[4][4] = {{0.f,0.f,0.f,0.f},{0.f,0.f,0.f,0.f},
                     {0.f,0.f,0.f,0.f},{0.f,0.f,0.f,0.f}};
  const float* xr = x + (size_t)(i0 + tr * 4) * 256;
  const float* wp = W + c0 + tc * 4;

#pragma unroll
  for (int k = 0; k < 256; k += 4) {
    float4 xv[4], wv[4];
#pragma unroll
    for (int i = 0; i < 4; ++i) xv[i] = *(const float4*)(xr + i * 256 + k);
#pragma unroll
    for (int j = 0; j < 4; ++j) wv[j] = *(const float4*)(wp + (size_t)(k + j) * 256);
    float xs[4][4] = {{xv[0].x, xv[0].y, xv[0].z, xv[0].w},
                      {xv[1].x, xv[1].y, xv[1].z, xv[1].w},
                      {xv[2].x, xv[2].y, xv[2].z, xv[2].w},
                      {xv[3].x, xv[3].y, xv[3].z, xv[3].w}};
#pragma unroll
    for (int kk = 0; kk < 4; ++kk)
#pragma unroll
      for (int i = 0; i < 4; ++i) {
        acc[i][0] = fmaf(xs[i][kk], wv[kk].x, acc[i][0]);
        acc[i][1] = fmaf(xs[i][kk], wv[kk].y, acc[i][1]);
        acc[i][2] = fmaf(xs[i][kk], wv[kk].z, acc[i][2]);
        acc[i][3] = fmaf(xs[i][kk], wv[kk].w, acc[i][3]);
      }
  }

  float4 a1v = *(const float4*)(a1 + tc * 4);
  float4 a2v = *(const float4*)(a2 + tc * 4);
#pragma unroll
  for (int i = 0; i < 4; ++i) {
    float s1 = acc[i][0]*a1v.x + acc[i][1]*a1v.y + acc[i][2]*a1v.z + acc[i][3]*a1v.w;
    float s2 = acc[i][0]*a2v.x + acc[i][1]*a2v.y + acc[i][2]*a2v.z + acc[i][3]*a2v.w;
#pragma unroll
    for (int off = 1; off < 16; off <<= 1) {
      s1 += __shfl_xor(s1, off);
      s2 += __shfl_xor(s2, off);
    }
    if (tc == 0) {
      int r = tr * 4 + i;
      siT[hh * NN + i0 + r] = s1 * LOG2E;
      float sjs = s2 * LOG2E;
      vv2T[hh * NN + i0 + r] =
          make_float2(__builtin_amdgcn_exp2f(sjs), __builtin_amdgcn_exp2f(0.2f * sjs));
      sjb[r] = sjs;
    }
    *(float4*)&hl[(tr * 4 + i) * 68 + tc * 4] =
        make_float4(acc[i][0], acc[i][1], acc[i][2], acc[i][3]);
  }
  __syncthreads();

  if (t < 64) {  // block-level sj max partial (64 rows)
    float v = sjb[t];
#pragma unroll
    for (int off = 1; off < 64; off <<= 1) v = fmaxf(v, __shfl_xor(v, off));
    if (t == 0) sjm[it * 4 + hh] = v;
  }

  // fragment-major hTf: 2 chunks of 32 j, subtile nt = wave id,
  // lane holds B-frag 16B: hT[d = nt*16+l16][j = i0 + ch*32 + quad*8 .. +7]
  const int nt = t >> 6, lane = t & 63, quad = lane >> 4, l16 = lane & 15;
#pragma unroll
  for (int ch = 0; ch < 2; ++ch) {
    bf16x8 h0;
#pragma unroll
    for (int jj = 0; jj < 8; ++jj)
      h0[jj] = (__bf16)hl[(ch * 32 + quad * 8 + jj) * 68 + nt * 16 + l16];
    *(bf16x8*)((char*)hTf +
               ((((size_t)hh * 128 + it * 2 + ch) * 4 + nt) << 10) + (lane << 4)) = h0;
  }
}

// ---------------- Kernel 2: masked softmax + PV (MFMA) ----------------
// grid (64 i-tiles of 64 rows, 4 heads, 2 j-splits), 256 threads = 4 waves;
// wave w owns j-offset w*64 within each 256-j window; 8 windows per block.
__global__ __launch_bounds__(256, 2) void gat_attn(
    const __bf16* __restrict__ hTf, const float* __restrict__ siT,
    const float2* __restrict__ vv2T, const float* __restrict__ sjm,
    const unsigned int* __restrict__ adjw,
    float* __restrict__ pacc, float* __restrict__ pl) {
  // LDS: hT buf0 [0,32768) | hT buf1 [32768,65536)
  // epilogue alias: accs f32[2][64][68] @0 (34816 B), lsum f32[2][64] @34816
  __shared__ __align__(16) char lds[65536];
  const int t = threadIdx.x;
  const int w = t >> 6, lane = t & 63, quad = lane >> 4, l16 = lane & 15;
  const int i0 = blockIdx.x * 64, hh = blockIdx.y, s = blockIdx.z;
  const int jbeg = s * 2048;

  // staging source: this wave's first chunk (chunk = 32 j = 4 KB), + lane*16
  const char* hsrc = (const char*)hTf +
      (((size_t)hh * 128 + (jbeg >> 5) + w * 2) << 12) + (lane << 4);
  const float2* vw = vv2T + (size_t)hh * NN + jbeg + w * 64;

  const unsigned int* mp[4];
#pragma unroll
  for (int mt = 0; mt < 4; ++mt)
    mp[mt] = adjw + (size_t)(i0 + mt * 16 + l16) * 128 + (jbeg >> 5) + w * 2;

  // ---- prefetch window 0: masks + vv2 (regs), hT (LDS buf0) ----
  uint2 mc[4], mn[4];
  float4 qc[2][4], qn[2][4];
#pragma unroll
  for (int mt = 0; mt < 4; ++mt) mc[mt] = *(const uint2*)mp[mt];
#pragma unroll
  for (int k = 0; k < 2; ++k) {
    const float4* qp = (const float4*)(vw + k * 32 + quad * 8);
#pragma unroll
    for (int c = 0; c < 4; ++c) qc[k][c] = qp[c];
  }
#pragma unroll
  for (int k = 0; k < 2; ++k)
#pragma unroll
    for (int nt = 0; nt < 4; ++nt)
      gl16(hsrc + ((k * 4 + nt) << 10),
           lds + (((w * 8 + k * 4 + nt) << 10) + (lane << 4)));

  // ---- per-row constants (overlaps staging) ----
  float vv = sjm[lane * 4 + hh];   // 64 tile-partials from gat_prep
#pragma unroll
  for (int off = 1; off < 64; off <<= 1) vv = fmaxf(vv, __shfl_xor(vv, off));
  float u[4], u2[4];
#pragma unroll
  for (int mt = 0; mt < 4; ++mt) {
    float sis = siT[hh * NN + i0 + mt * 16 + l16];
    float tt = sis + vv;
    float m = fmaxf(tt, 0.2f * tt);   // leaky monotone -> valid row-max upper bound
    u[mt] = __builtin_amdgcn_exp2f(sis - m);
    u2[mt] = __builtin_amdgcn_exp2f(0.2f * sis - m);
  }

  bf16x8 ones;
#pragma unroll
  for (int ii = 0; ii < 8; ++ii) ones[ii] = (__bf16)1.0f;

  floatx4 zv = {0.f, 0.f, 0.f, 0.f};
  floatx4 acc[4][4], lacc[4];
#pragma unroll
  for (int mt = 0; mt < 4; ++mt) {
    lacc[mt] = zv;
#pragma unroll
    for (int nt = 0; nt < 4; ++nt) acc[mt][nt] = zv;
  }

  __syncthreads();   // window 0 staged

  for (int win = 0; win < 8; ++win) {
    const int p = win & 1;
    const char* hb = lds + p * 32768;

    if (win + 1 < 8) {  // prefetch next window: regs first, then LDS staging
#pragma unroll
      for (int mt = 0; mt < 4; ++mt)
        mn[mt] = *(const uint2*)(mp[mt] + (win + 1) * 8);
#pragma unroll
      for (int k = 0; k < 2; ++k) {
        const float4* qp = (const float4*)(vw + (win + 1) * 256 + k * 32 + quad * 8);
#pragma unroll
        for (int c = 0; c < 4; ++c) qn[k][c] = qp[c];
      }
      char* hbn = lds + (p ^ 1) * 32768;
      const char* hs = hsrc + (win + 1) * 32768;
#pragma unroll
      for (int k = 0; k < 2; ++k)
#pragma unroll
        for (int nt = 0; nt < 4; ++nt)
          gl16(hs + ((k * 4 + nt) << 10),
               hbn + (((w * 8 + k * 4 + nt) << 10) + (lane << 4)));
    }

#pragma unroll
    for (int k = 0; k < 2; ++k) {
      bf16x8 bfr[4];
#pragma unroll
      for (int nt = 0; nt < 4; ++nt)
        bfr[nt] = *(const bf16x8*)(hb + ((w * 8 + k * 4 + nt) << 10) + (lane << 4));
#pragma unroll
      for (int mt = 0; mt < 4; ++mt) {
        unsigned int m8 = (k ? mc[mt].y : mc[mt].x) >> (quad * 8);
        bf16x8 af;
#pragma unroll
        for (int c = 0; c < 4; ++c) {
          float p0 = fmaxf(u[mt] * qc[k][c].x, u2[mt] * qc[k][c].y);
          float p1 = fmaxf(u[mt] * qc[k][c].z, u2[mt] * qc[k][c].w);
          // sign-extended 1-bit extract -> bitwise AND (2 VALU, no cmp/cndmask)
          int b0 = ((int)(m8 << (31 - 2 * c))) >> 31;
          int b1 = ((int)(m8 << (30 - 2 * c))) >> 31;
          af[2 * c]     = (__bf16)__uint_as_float(__float_as_uint(p0) & (unsigned)b0);
          af[2 * c + 1] = (__bf16)__uint_as_float(__float_as_uint(p1) & (unsigned)b1);
        }
#pragma unroll
        for (int nt = 0; nt < 4; ++nt)
          acc[mt][nt] = __builtin_amdgcn_mfma_f32_16x16x32_bf16(af, bfr[nt],
                                                                acc[mt][nt], 0, 0, 0);
        lacc[mt] = __builtin_amdgcn_mfma_f32_16x16x32_bf16(af, ones, lacc[mt], 0, 0, 0);
      }
    }
#pragma unroll
    for (int mt = 0; mt < 4; ++mt) mc[mt] = mn[mt];
#pragma unroll
    for (int k = 0; k < 2; ++k)
#pragma unroll
      for (int c = 0; c < 4; ++c) qc[k][c] = qn[k][c];
    __syncthreads();
  }

  // epilogue: combine the 4 j-split waves in LDS (aliases dead staging bufs)
  float* accs = (float*)lds;             // [2][64][68]
  float* lsum = (float*)(lds + 34816);   // [2][64]
  // C layout: row = mt*16 + quad*4 + reg, col = nt*16 + l16
  if (w < 2) {
#pragma unroll
    for (int mt = 0; mt < 4; ++mt)
#pragma unroll
      for (int reg = 0; reg < 4; ++reg) {
        int row = mt * 16 + quad * 4 + reg;
        float* ap = accs + (w * 64 + row) * 68;
#pragma unroll
        for (int nt = 0; nt < 4; ++nt)
          ap[nt * 16 + l16] = acc[mt][nt][reg];
        if (l16 == 0) lsum[w * 64 + row] = lacc[mt][reg];
      }
  }
  __syncthreads();
  if (w >= 2) {
    const int bb = w - 2;
#pragma unroll
    for (int mt = 0; mt < 4; ++mt)
#pragma unroll
      for (int reg = 0; reg < 4; ++reg) {
        int row = mt * 16 + quad * 4 + reg;
        float* ap = accs + (bb * 64 + row) * 68;
#pragma unroll
        for (int nt = 0; nt < 4; ++nt)
          ap[nt * 16 + l16] += acc[mt][nt][reg];
        if (l16 == 0) lsum[bb * 64 + row] += lacc[mt][reg];
      }
  }
  __syncthreads();

  // write partials: r = t>>2 (64 rows), cbase = (t&3)*16 (16 cols per thread)
  const int r = t >> 2, cb = (t & 3) * 16;
  float* op = pacc + (size_t)s * NN * 256 + (size_t)(i0 + r) * 256 + hh * 64 + cb;
#pragma unroll
  for (int c4 = 0; c4 < 4; ++c4) {
    int c = cb + c4 * 4;
    float4 o;
    o.x = accs[r * 68 + c + 0] + accs[(64 + r) * 68 + c + 0];
    o.y = accs[r * 68 + c + 1] + accs[(64 + r) * 68 + c + 1];
    o.z = accs[r * 68 + c + 2] + accs[(64 + r) * 68 + c + 2];
    o.w = accs[r * 68 + c + 3] + accs[(64 + r) * 68 + c + 3];
    *(float4*)(op + c4 * 4) = o;
  }
  if (t < 64)
    pl[(size_t)s * NN * 4 + (i0 + t) * 4 + hh] = lsum[t] + lsum[64 + t];
}

// ---------------- Kernel 3: combine j-splits + normalize ----------------
__global__ __launch_bounds__(256) void gat_reduce(
    const float* __restrict__ pacc, const float* __restrict__ pl,
    float* __restrict__ out) {
  const int e4 = blockIdx.x * 256 + threadIdx.x;
  const int e = e4 * 4;                 // e = i*256 + h*64 + d
  const int i = e >> 8;
  const int h = (e & 255) >> 6;
  float4 a0 = *(const float4*)(pacc + e);
  float4 a1 = *(const float4*)(pacc + (size_t)NN * 256 + e);
  float l = pl[i * 4 + h] + pl[(size_t)NN * 4 + i * 4 + h];
  float inv = 1.0f / l;
  *(float4*)(out + e) = make_float4((a0.x + a1.x) * inv, (a0.y + a1.y) * inv,
                                    (a0.z + a1.z) * inv, (a0.w + a1.w) * inv);
}

extern "C" void kernel_launch(void* const* d_in, const int* in_sizes, int n_in,
                              void* d_out, int out_size, void* d_ws, size_t ws_size,
                              hipStream_t stream) {
  const float* x  = (const float*)d_in[0];
  const int*   adj = (const int*)d_in[1];
  const float* W  = (const float*)d_in[2];
  const float* a1 = (const float*)d_in[3];
  const float* a2 = (const float*)d_in[4];
  float* out = (float*)d_out;
  char* ws = (char*)d_ws;

  // ws layout (bytes):
  //   hTf  bf16   [4][128][4][1024B] @ 0   (2 MiB, fragment-major)
  //   siT  f32    [4][4096]     @ 2097152  (64 KiB)
  //   vv2T f32x2  [4][4096]     @ 2162688  (128 KiB)
  //   sjm  f32    [64][4]       @ 2293760  (1 KiB)
  //   adjb u8     [4096][512]   @ 2295808  (2 MiB bitmask)
  //   pacc f32    [2][4096][256]@ 4392960  (8 MiB)
  //   pl   f32    [2][4096][4]  @ 12781568 (128 KiB)
  __bf16* hTf  = (__bf16*)ws;
  float*  siT  = (float*)(ws + 2097152);
  float2* vv2T = (float2*)(ws + 2162688);
  float*  sjm  = (float*)(ws + 2293760);
  unsigned char* adjb = (unsigned char*)(ws + 2295808);
  float*  pacc = (float*)(ws + 4392960);
  float*  pl   = (float*)(ws + 12781568);

  gat_prep<<<2304, 256, 0, stream>>>(x, W, a1, a2, adj, hTf, siT, vv2T, sjm, adjb);
  gat_attn<<<dim3(64, 4, 2), 256, 0, stream>>>(hTf, siT, vv2T, sjm,
                                               (const unsigned int*)adjb, pacc, pl);
  gat_reduce<<<1024, 256, 0, stream>>>(pacc, pl, out);
}

// Round 10
// 161.041 us; speedup vs baseline: 3.3496x; 3.3496x over previous
//
#include <hip/hip_runtime.h>
#include <hip/hip_bf16.h>

// GAT: N=4096 nodes, IN_F=256, H=4 heads, D=64.
// K1 gat_prep : fused. blocks [0,512): h = x@W (fp32, rolled k-loop, unroll 2,
//               VGPR cap 256 -> loads batched not serialized), siT = <h,a1>*log2e,
//               vv2T = {exp2(sj), exp2(0.2*sj)}, hTf bf16 fragment-major
//               [h][j-chunk][nt][lane], per-block sj-max partials.
//               blocks [512,2560): adj (64 MB int) -> adjb bitmask (2 MB),
//               1 dword/thread, 8 int4 in flight (streams behind the GEMM).
// K2 gat_attn : masked softmax + PV via mfma_16x16x32_bf16.
//               m_i = leaky(si + max_j sj) upper bound -> pure-sum softmax.
//               64-row tiles x 4 heads x 2 j-splits; 256-j LDS windows double-
//               buffered (32KBx2), staged with contiguous-1KB global_load_lds;
//               masks+vv2 register-prefetched (drained free by window barrier).
// K3 gat_reduce: out = (p0+p1)/(l0+l1).

typedef __bf16 bf16x8 __attribute__((ext_vector_type(8)));
typedef float floatx4 __attribute__((ext_vector_type(4)));

#define LOG2E 1.4426950408889634f
#define NN 4096

__device__ __forceinline__ void gl16(const void* g, void* l) {
  __builtin_amdgcn_global_load_lds(
      (const __attribute__((address_space(1))) unsigned int*)g,
      (__attribute__((address_space(3))) unsigned int*)l, 16, 0, 0);
}

// ---------------- Kernel 1: fused prep + pack ----------------
// blocks [0,512): prep (it = b&127 -> 32-row tile, hh = b>>7)
// blocks [512,2560): pack (thread -> 4 mask bytes, 8 int4 in flight)
__global__ __launch_bounds__(256, 2) void gat_prep(
    const float* __restrict__ x, const float* __restrict__ W,
    const float* __restrict__ a1, const float* __restrict__ a2,
    const int* __restrict__ adj, __bf16* __restrict__ hTf,
    float* __restrict__ siT, float2* __restrict__ vv2T, float* __restrict__ sjm,
    unsigned char* __restrict__ adjb) {
  const int b = blockIdx.x;
  const int t = threadIdx.x;

  if (b >= 512) {  // ---- pack: adj -> bitmask, dword per thread ----
    const int T = (b - 512) * 256 + t;      // dword index, [0, 512K)
    const int* p = adj + (size_t)T * 32;    // 32 ints = 128 B contiguous
    int4 v[8];
#pragma unroll
    for (int j = 0; j < 8; ++j) v[j] = *(const int4*)(p + j * 4);
    unsigned int m = 0;
#pragma unroll
    for (int c = 0; c < 4; ++c) {
      int4 a = v[2 * c], bb = v[2 * c + 1];
      unsigned int mm = 0;
      mm |= (a.x != 0) ? 1u : 0u;
      mm |= (a.y != 0) ? 2u : 0u;
      mm |= (a.z != 0) ? 4u : 0u;
      mm |= (a.w != 0) ? 8u : 0u;
      mm |= (bb.x != 0) ? 16u : 0u;
      mm |= (bb.y != 0) ? 32u : 0u;
      mm |= (bb.z != 0) ? 64u : 0u;
      mm |= (bb.w != 0) ? 128u : 0u;
      m |= mm << (c * 8);
    }
    ((unsigned int*)adjb)[T] = m;
    return;
  }

  // ---- prep: 32 rows x 64 cols per block, 2x4 micro-tile per thread ----
  __shared__ float hl[32 * 68];
  __shared__ float sjb[32];
  const int it = b & 127, hh = b >> 7;
  const int i0 = it * 32, c0 = hh * 64;
  const int tr = t >> 4, tc = t & 15;

  float acc[2][4] = {{0.f,0.f,0.f,0.f},{0.f,0.f,0.f,0.f}};
  const float* xr = x + (size_t)(i0 + tr * 2) * 256;
  const float* wp = W + c0 + tc * 4;
#pragma unroll 2
  for (int k = 0; k < 256; k += 4) {
    float4 xv0 = *(const float4*)(xr + k);
    float4 xv1 = *(const float4*)(xr + 256 + k);
    float4 wv[4];
#pragma unroll
    for (int j = 0; j < 4; ++j) wv[j] = *(const float4*)(wp + (size_t)(k + j) * 256);
    float xs[2][4] = {{xv0.x, xv0.y, xv0.z, xv0.w},
                      {xv1.x, xv1.y, xv1.z, xv1.w}};
#pragma unroll
    for (int kk = 0; kk < 4; ++kk) {
#pragma unroll
      for (int i = 0; i < 2; ++i) {
        acc[i][0] = fmaf(xs[i][kk], wv[kk].x, acc[i][0]);
        acc[i][1] = fmaf(xs[i][kk], wv[kk].y, acc[i][1]);
        acc[i][2] = fmaf(xs[i][kk], wv[kk].z, acc[i][2]);
        acc[i][3] = fmaf(xs[i][kk], wv[kk].w, acc[i][3]);
      }
    }
  }

  float4 a1v = *(const float4*)(a1 + tc * 4);
  float4 a2v = *(const float4*)(a2 + tc * 4);
#pragma unroll
  for (int i = 0; i < 2; ++i) {
    float s1 = acc[i][0]*a1v.x + acc[i][1]*a1v.y + acc[i][2]*a1v.z + acc[i][3]*a1v.w;
    float s2 = acc[i][0]*a2v.x + acc[i][1]*a2v.y + acc[i][2]*a2v.z + acc[i][3]*a2v.w;
#pragma unroll
    for (int off = 1; off < 16; off <<= 1) {
      s1 += __shfl_xor(s1, off);
      s2 += __shfl_xor(s2, off);
    }
    if (tc == 0) {
      int r = tr * 2 + i;
      siT[hh * NN + i0 + r] = s1 * LOG2E;
      float sjs = s2 * LOG2E;
      vv2T[hh * NN + i0 + r] =
          make_float2(__builtin_amdgcn_exp2f(sjs), __builtin_amdgcn_exp2f(0.2f * sjs));
      sjb[r] = sjs;
    }
    *(float4*)&hl[(tr * 2 + i) * 68 + tc * 4] =
        make_float4(acc[i][0], acc[i][1], acc[i][2], acc[i][3]);
  }
  __syncthreads();

  if (t < 32) {
    float v = sjb[t];
#pragma unroll
    for (int off = 1; off < 32; off <<= 1) v = fmaxf(v, __shfl_xor(v, off));
    if (t == 0) sjm[it * 4 + hh] = v;
  }

  // fragment-major hTf: chunk it (j = i0 + quad*8 + jj), subtile nt = wave id,
  // lane holds B-frag 16B: hT[d = nt*16+l16][j = i0 + quad*8 .. +7]
  const int nt = t >> 6, lane = t & 63, quad = lane >> 4, l16 = lane & 15;
  bf16x8 h0;
#pragma unroll
  for (int jj = 0; jj < 8; ++jj)
    h0[jj] = (__bf16)hl[(quad * 8 + jj) * 68 + nt * 16 + l16];
  *(bf16x8*)((char*)hTf + ((((size_t)hh * 128 + it) * 4 + nt) << 10) + (lane << 4)) = h0;
}

// ---------------- Kernel 2: masked softmax + PV (MFMA) ----------------
// grid (64 i-tiles of 64 rows, 4 heads, 2 j-splits), 256 threads = 4 waves;
// wave w owns j-offset w*64 within each 256-j window; 8 windows per block.
__global__ __launch_bounds__(256, 2) void gat_attn(
    const __bf16* __restrict__ hTf, const float* __restrict__ siT,
    const float2* __restrict__ vv2T, const float* __restrict__ sjm,
    const unsigned int* __restrict__ adjw,
    float* __restrict__ pacc, float* __restrict__ pl) {
  // LDS: hT buf0 [0,32768) | hT buf1 [32768,65536)
  // epilogue alias: accs f32[2][64][68] @0 (34816 B), lsum f32[2][64] @34816
  __shared__ __align__(16) char lds[65536];
  const int t = threadIdx.x;
  const int w = t >> 6, lane = t & 63, quad = lane >> 4, l16 = lane & 15;
  const int i0 = blockIdx.x * 64, hh = blockIdx.y, s = blockIdx.z;
  const int jbeg = s * 2048;

  // staging source: this wave's first chunk (chunk = 32 j = 4 KB), + lane*16
  const char* hsrc = (const char*)hTf +
      (((size_t)hh * 128 + (jbeg >> 5) + w * 2) << 12) + (lane << 4);
  const float2* vw = vv2T + (size_t)hh * NN + jbeg + w * 64;

  const unsigned int* mp[4];
#pragma unroll
  for (int mt = 0; mt < 4; ++mt)
    mp[mt] = adjw + (size_t)(i0 + mt * 16 + l16) * 128 + (jbeg >> 5) + w * 2;

  // ---- prefetch window 0: masks + vv2 (regs), hT (LDS buf0) ----
  uint2 mc[4], mn[4];
  float4 qc[2][4], qn[2][4];
#pragma unroll
  for (int mt = 0; mt < 4; ++mt) mc[mt] = *(const uint2*)mp[mt];
#pragma unroll
  for (int k = 0; k < 2; ++k) {
    const float4* qp = (const float4*)(vw + k * 32 + quad * 8);
#pragma unroll
    for (int c = 0; c < 4; ++c) qc[k][c] = qp[c];
  }
#pragma unroll
  for (int k = 0; k < 2; ++k)
#pragma unroll
    for (int nt = 0; nt < 4; ++nt)
      gl16(hsrc + ((k * 4 + nt) << 10),
           lds + (((w * 8 + k * 4 + nt) << 10) + (lane << 4)));

  // ---- per-row constants (overlaps staging) ----
  float vv = fmaxf(sjm[lane * 4 + hh], sjm[(lane + 64) * 4 + hh]);
#pragma unroll
  for (int off = 1; off < 64; off <<= 1) vv = fmaxf(vv, __shfl_xor(vv, off));
  float u[4], u2[4];
#pragma unroll
  for (int mt = 0; mt < 4; ++mt) {
    float sis = siT[hh * NN + i0 + mt * 16 + l16];
    float tt = sis + vv;
    float m = fmaxf(tt, 0.2f * tt);   // leaky monotone -> valid row-max upper bound
    u[mt] = __builtin_amdgcn_exp2f(sis - m);
    u2[mt] = __builtin_amdgcn_exp2f(0.2f * sis - m);
  }

  bf16x8 ones;
#pragma unroll
  for (int ii = 0; ii < 8; ++ii) ones[ii] = (__bf16)1.0f;

  floatx4 zv = {0.f, 0.f, 0.f, 0.f};
  floatx4 acc[4][4], lacc[4];
#pragma unroll
  for (int mt = 0; mt < 4; ++mt) {
    lacc[mt] = zv;
#pragma unroll
    for (int nt = 0; nt < 4; ++nt) acc[mt][nt] = zv;
  }

  __syncthreads();   // window 0 staged

  for (int win = 0; win < 8; ++win) {
    const int p = win & 1;
    const char* hb = lds + p * 32768;

    if (win + 1 < 8) {  // prefetch next window: regs first, then LDS staging
#pragma unroll
      for (int mt = 0; mt < 4; ++mt)
        mn[mt] = *(const uint2*)(mp[mt] + (win + 1) * 8);
#pragma unroll
      for (int k = 0; k < 2; ++k) {
        const float4* qp = (const float4*)(vw + (win + 1) * 256 + k * 32 + quad * 8);
#pragma unroll
        for (int c = 0; c < 4; ++c) qn[k][c] = qp[c];
      }
      char* hbn = lds + (p ^ 1) * 32768;
      const char* hs = hsrc + (win + 1) * 32768;
#pragma unroll
      for (int k = 0; k < 2; ++k)
#pragma unroll
        for (int nt = 0; nt < 4; ++nt)
          gl16(hs + ((k * 4 + nt) << 10),
               hbn + (((w * 8 + k * 4 + nt) << 10) + (lane << 4)));
    }

#pragma unroll
    for (int k = 0; k < 2; ++k) {
      bf16x8 bfr[4];
#pragma unroll
      for (int nt = 0; nt < 4; ++nt)
        bfr[nt] = *(const bf16x8*)(hb + ((w * 8 + k * 4 + nt) << 10) + (lane << 4));
#pragma unroll
      for (int mt = 0; mt < 4; ++mt) {
        unsigned int m8 = (k ? mc[mt].y : mc[mt].x) >> (quad * 8);
        bf16x8 af;
#pragma unroll
        for (int c = 0; c < 4; ++c) {
          float p0 = fmaxf(u[mt] * qc[k][c].x, u2[mt] * qc[k][c].y);
          float p1 = fmaxf(u[mt] * qc[k][c].z, u2[mt] * qc[k][c].w);
          // sign-extended 1-bit extract -> bitwise AND (2 VALU, no cmp/cndmask)
          int b0 = ((int)(m8 << (31 - 2 * c))) >> 31;
          int b1 = ((int)(m8 << (30 - 2 * c))) >> 31;
          af[2 * c]     = (__bf16)__uint_as_float(__float_as_uint(p0) & (unsigned)b0);
          af[2 * c + 1] = (__bf16)__uint_as_float(__float_as_uint(p1) & (unsigned)b1);
        }
#pragma unroll
        for (int nt = 0; nt < 4; ++nt)
          acc[mt][nt] = __builtin_amdgcn_mfma_f32_16x16x32_bf16(af, bfr[nt],
                                                                acc[mt][nt], 0, 0, 0);
        lacc[mt] = __builtin_amdgcn_mfma_f32_16x16x32_bf16(af, ones, lacc[mt], 0, 0, 0);
      }
    }
#pragma unroll
    for (int mt = 0; mt < 4; ++mt) mc[mt] = mn[mt];
#pragma unroll
    for (int k = 0; k < 2; ++k)
#pragma unroll
      for (int c = 0; c < 4; ++c) qc[k][c] = qn[k][c];
    __syncthreads();
  }

  // epilogue: combine the 4 j-split waves in LDS (aliases dead staging bufs)
  float* accs = (float*)lds;             // [2][64][68]
  float* lsum = (float*)(lds + 34816);   // [2][64]
  // C layout: row = mt*16 + quad*4 + reg, col = nt*16 + l16
  if (w < 2) {
#pragma unroll
    for (int mt = 0; mt < 4; ++mt)
#pragma unroll
      for (int reg = 0; reg < 4; ++reg) {
        int row = mt * 16 + quad * 4 + reg;
        float* ap = accs + (w * 64 + row) * 68;
#pragma unroll
        for (int nt = 0; nt < 4; ++nt)
          ap[nt * 16 + l16] = acc[mt][nt][reg];
        if (l16 == 0) lsum[w * 64 + row] = lacc[mt][reg];
      }
  }
  __syncthreads();
  if (w >= 2) {
    const int bb = w - 2;
#pragma unroll
    for (int mt = 0; mt < 4; ++mt)
#pragma unroll
      for (int reg = 0; reg < 4; ++reg) {
        int row = mt * 16 + quad * 4 + reg;
        float* ap = accs + (bb * 64 + row) * 68;
#pragma unroll
        for (int nt = 0; nt < 4; ++nt)
          ap[nt * 16 + l16] += acc[mt][nt][reg];
        if (l16 == 0) lsum[bb * 64 + row] += lacc[mt][reg];
      }
  }
  __syncthreads();

  // write partials: r = t>>2 (64 rows), cbase = (t&3)*16 (16 cols per thread)
  const int r = t >> 2, cb = (t & 3) * 16;
  float* op = pacc + (size_t)s * NN * 256 + (size_t)(i0 + r) * 256 + hh * 64 + cb;
#pragma unroll
  for (int c4 = 0; c4 < 4; ++c4) {
    int c = cb + c4 * 4;
    float4 o;
    o.x = accs[r * 68 + c + 0] + accs[(64 + r) * 68 + c + 0];
    o.y = accs[r * 68 + c + 1] + accs[(64 + r) * 68 + c + 1];
    o.z = accs[r * 68 + c + 2] + accs[(64 + r) * 68 + c + 2];
    o.w = accs[r * 68 + c + 3] + accs[(64 + r) * 68 + c + 3];
    *(float4*)(op + c4 * 4) = o;
  }
  if (t < 64)
    pl[(size_t)s * NN * 4 + (i0 + t) * 4 + hh] = lsum[t] + lsum[64 + t];
}

// ---------------- Kernel 3: combine j-splits + normalize ----------------
__global__ __launch_bounds__(256) void gat_reduce(
    const float* __restrict__ pacc, const float* __restrict__ pl,
    float* __restrict__ out) {
  const int e4 = blockIdx.x * 256 + threadIdx.x;
  const int e = e4 * 4;                 // e = i*256 + h*64 + d
  const int i = e >> 8;
  const int h = (e & 255) >> 6;
  float4 a0 = *(const float4*)(pacc + e);
  float4 a1 = *(const float4*)(pacc + (size_t)NN * 256 + e);
  float l = pl[i * 4 + h] + pl[(size_t)NN * 4 + i * 4 + h];
  float inv = 1.0f / l;
  *(float4*)(out + e) = make_float4((a0.x + a1.x) * inv, (a0.y + a1.y) * inv,
                                    (a0.z + a1.z) * inv, (a0.w + a1.w) * inv);
}

extern "C" void kernel_launch(void* const* d_in, const int* in_sizes, int n_in,
                              void* d_out, int out_size, void* d_ws, size_t ws_size,
                              hipStream_t stream) {
  const float* x  = (const float*)d_in[0];
  const int*   adj = (const int*)d_in[1];
  const float* W  = (const float*)d_in[2];
  const float* a1 = (const float*)d_in[3];
  const float* a2 = (const float*)d_in[4];
  float* out = (float*)d_out;
  char* ws = (char*)d_ws;

  // ws layout (bytes):
  //   hTf  bf16   [4][128][4][1024B] @ 0   (2 MiB, fragment-major)
  //   siT  f32    [4][4096]     @ 2097152  (64 KiB)
  //   vv2T f32x2  [4][4096]     @ 2162688  (128 KiB)
  //   sjm  f32    [128][4]      @ 2293760  (2 KiB)
  //   adjb u8     [4096][512]   @ 2295808  (2 MiB bitmask)
  //   pacc f32    [2][4096][256]@ 4392960  (8 MiB)
  //   pl   f32    [2][4096][4]  @ 12781568 (128 KiB)
  __bf16* hTf  = (__bf16*)ws;
  float*  siT  = (float*)(ws + 2097152);
  float2* vv2T = (float2*)(ws + 2162688);
  float*  sjm  = (float*)(ws + 2293760);
  unsigned char* adjb = (unsigned char*)(ws + 2295808);
  float*  pacc = (float*)(ws + 4392960);
  float*  pl   = (float*)(ws + 12781568);

  gat_prep<<<2560, 256, 0, stream>>>(x, W, a1, a2, adj, hTf, siT, vv2T, sjm, adjb);
  gat_attn<<<dim3(64, 4, 2), 256, 0, stream>>>(hTf, siT, vv2T, sjm,
                                               (const unsigned int*)adjb, pacc, pl);
  gat_reduce<<<1024, 256, 0, stream>>>(pacc, pl, out);
}